// Round 9
// baseline (370.607 us; speedup 1.0000x reference)
//
#include <hip/hip_runtime.h>
#include <hip/hip_bf16.h>
#include <cstdint>

// ---------------------------------------------------------------------------
// SelfAttention: q,k,v = x@W{q,k,v}^T + b ; P = softmax(qk^T/sqrt(H)) ; out = P@v
// B=4, S=2048, H=I=1024. fp32 I/O, bf16 MFMA internally (tol 6.25e-3).
// R13: R12 + __builtin_nontemporal_store on all large output streams
//      (scores E, PV w + out, QKV q/k/vt). R12 counters show FETCH_SIZE
//      excess ~= store volume on every GEMM (write-allocate line fetches);
//      PV is BW-bound (4.1 TB/s, 290 MB vs 151 mandatory) so nt stores
//      convert directly to time there.
// ---------------------------------------------------------------------------

typedef __bf16 bf16x8 __attribute__((ext_vector_type(8)));
typedef float  f32x4  __attribute__((ext_vector_type(4)));

__device__ __forceinline__ void load_lds16(const __bf16* g, __bf16* l) {
    __builtin_amdgcn_global_load_lds(
        (const __attribute__((address_space(1))) void*)g,
        (__attribute__((address_space(3))) void*)l,
        16, 0, 0);
}

// ------------- merged fp32->bf16 converts + bias pack (1 launch) -----------
__global__ __launch_bounds__(256) void cvt_all(
        const float* __restrict__ x,
        const float* __restrict__ wq, const float* __restrict__ wk,
        const float* __restrict__ wv,
        const float* __restrict__ bq, const float* __restrict__ bk,
        const float* __restrict__ bv,
        __bf16* __restrict__ xb, __bf16* __restrict__ wb,
        float* __restrict__ bias3) {
    const long NX = 1048576, NW = 131072;
    long i = (long)blockIdx.x * 256 + threadIdx.x;
    const float* src; __bf16* dst; long c;
    if (i < NX) { src = x; dst = xb; c = i; }
    else if (i < NX + 3 * NW) {
        long j = i - NX;
        src = (j < NW) ? wq : (j < 2 * NW) ? wk : wv;
        c = j % NW;
        dst = wb + (j / NW) * (NW * 8);
    } else if (i < NX + 3 * NW + 384) {
        long cidx = i - (NX + 3 * NW);
        int seg = (int)(cidx >> 7);
        const float* bs = (seg == 0) ? bq : (seg == 1) ? bk : bv;
        long off = (cidx & 127) * 8;
        float4 a = *(const float4*)(bs + off);
        float4 b = *(const float4*)(bs + off + 4);
        *(float4*)(bias3 + cidx * 8)     = a;
        *(float4*)(bias3 + cidx * 8 + 4) = b;
        return;
    } else return;
    const float4* s4 = (const float4*)src;
    float4 a = s4[2 * c], b = s4[2 * c + 1];
    bf16x8 o;
    o[0] = (__bf16)a.x; o[1] = (__bf16)a.y; o[2] = (__bf16)a.z; o[3] = (__bf16)a.w;
    o[4] = (__bf16)b.x; o[5] = (__bf16)b.y; o[6] = (__bf16)b.z; o[7] = (__bf16)b.w;
    ((bf16x8*)dst)[c] = o;
}

// ---------------- NT bf16 GEMM: C[m,n] = sum_k A[m,k] * Bt[n,k] ------------
// 128x128 tile, BK=64, 4 waves (2x2 of 64x64), 16x16x32 MFMA, 4x4 frags/wave.
// LDS: 16B chunks, chunk (row,cs) holds cg = cs ^ (row&7).  Zero conflicts.
// MODE 0: fused QKV. n<2048 -> bf16=acc+bias to C0/C1 [m][n&1023];
//         n>=2048 -> V: LDS-transposed, written as vt[h][t] to C2.
// MODE 1: scores: bf16 E=exp(acc*scale) -> C0 (p_bf); row partial sums ->
//         C1 = psum[z][32][2048] (one writer per (z,nb2,row), no atomics).
// MODE 2: PV on unnormalized E: linv from psum (C1); epilogue writes f32
//         attention weights to C2 for owned k-chunks (E re-read from global)
//         and f32 = acc*linv -> C0 (weighted sum).
template <int MODE>
__global__ __launch_bounds__(256, 4) void gemm_nt(
        const __bf16* __restrict__ A, const __bf16* __restrict__ Bt,
        void* __restrict__ C0, void* __restrict__ C1, void* __restrict__ C2,
        const float* __restrict__ bias,
        int lda, int ldb, int ldc, long sA, long sB, long sC,
        int K, float scale) {
    __shared__ __bf16 smem[16384];      // lA | lB, reused as transpose buffer
    __shared__ float linv[128];         // MODE 2: per-row 1/sum
    __bf16* lA = smem;
    __bf16* lB = smem + 8192;

    const int tid  = threadIdx.x;
    const int lane = tid & 63;
    const int wave = tid >> 6;
    const int mblk = blockIdx.y * 128;
    const int nblk = blockIdx.x * 128;
    const int z    = blockIdx.z;
    A  += (long)z * sA;
    Bt += (long)z * sB;

    const int wm = (wave >> 1) * 64;
    const int wn = (wave & 1) * 64;

    f32x4 zero = {0.f, 0.f, 0.f, 0.f};
    f32x4 acc[4][4];
#pragma unroll
    for (int i = 0; i < 4; ++i)
#pragma unroll
        for (int j = 0; j < 4; ++j) acc[i][j] = zero;

    const int rsel = lane & 15;
    const int quad = lane >> 4;

    int srow[4], scol[4];
#pragma unroll
    for (int it = 0; it < 4; ++it) {
        int s  = tid + it * 256;
        srow[it] = s >> 3;
        scol[it] = ((s & 7) ^ (srow[it] & 7)) * 8;
    }

    if constexpr (MODE == 2) {
        // build linv[128] = 1/rowsum from 32 partials (coalesced, L2-hot)
        if (tid < 128) {
            const float* ps = (const float*)C1 + (long)z * 65536 + (mblk + tid);
            float ssum = 0.f;
#pragma unroll
            for (int nb = 0; nb < 32; ++nb) ssum += ps[nb * 2048];
            linv[tid] = 1.f / ssum;
        }
        // first in-loop __syncthreads() publishes linv before any use
    }

    for (int k0 = 0; k0 < K; k0 += 64) {
#pragma unroll
        for (int it = 0; it < 4; ++it) {
            int s = tid + it * 256;
            load_lds16(A  + (long)(mblk + srow[it]) * lda + k0 + scol[it], lA + s * 8);
            load_lds16(Bt + (long)(nblk + srow[it]) * ldb + k0 + scol[it], lB + s * 8);
        }
        __syncthreads();

#pragma unroll
        for (int half = 0; half < 2; ++half) {
            const int cq = quad + half * 4;
            bf16x8 fa[4], fb[4];
#pragma unroll
            for (int i = 0; i < 4; ++i) {
                int ra = wm + i * 16 + rsel;
                fa[i] = *(const bf16x8*)&lA[(ra * 8 + (cq ^ (ra & 7))) * 8];
                int rb = wn + i * 16 + rsel;
                fb[i] = *(const bf16x8*)&lB[(rb * 8 + (cq ^ (rb & 7))) * 8];
            }
#pragma unroll
            for (int i = 0; i < 4; ++i)
#pragma unroll
                for (int j = 0; j < 4; ++j)
                    acc[i][j] = __builtin_amdgcn_mfma_f32_16x16x32_bf16(
                        fa[i], fb[j], acc[i][j], 0, 0, 0);
        }
        __syncthreads();
    }

    // epilogue: lane holds C[m = wm+i*16+quad*4+r][n = wn+j*16+rsel]
    const int rq = quad * 4;
    if constexpr (MODE == 0) {
        if (nblk >= 2048) {
            // ---- V path: transpose tile via LDS, store vt[h][t] ----
            __bf16* tbuf = smem;
#pragma unroll
            for (int i = 0; i < 4; ++i) {
#pragma unroll
                for (int j = 0; j < 4; ++j) {
                    const int n_loc = wn + j * 16 + rsel;
                    const float bv = bias[nblk + n_loc];
                    const int m_loc = wm + i * 16 + rq;       // +r, r=0..3
                    const int c  = m_loc >> 3;
                    const int cs = c ^ (n_loc & 15);
                    __bf16* dst = &tbuf[n_loc * 128 + cs * 8 + (m_loc & 7)];
                    __bf16 tmp[4];
#pragma unroll
                    for (int r = 0; r < 4; ++r) tmp[r] = (__bf16)(acc[i][j][r] + bv);
                    *(uint64_t*)dst = *(const uint64_t*)tmp;
                }
            }
            __syncthreads();
            {
                __bf16* vt = (__bf16*)C2;
                const int n_loc = tid & 127;
                const int cpart = tid >> 7;
                const long b = mblk >> 11;                    // batch
                const long t0 = mblk & 2047;
                const long h  = nblk - 2048 + n_loc;
                __bf16* gdst = vt + b * (1024L * 2048) + h * 2048 + t0;
#pragma unroll
                for (int s = 0; s < 8; ++s) {
                    int c  = cpart * 8 + s;
                    int cs = c ^ (n_loc & 15);
                    bf16x8 vchunk = *(const bf16x8*)&tbuf[n_loc * 128 + cs * 8];
                    __builtin_nontemporal_store(vchunk, (bf16x8*)(gdst + c * 8));
                }
            }
        } else {
            // ---- Q/K path: normal [m][n] bf16 store ----
#pragma unroll
            for (int i = 0; i < 4; ++i) {
#pragma unroll
                for (int j = 0; j < 4; ++j) {
                    const int n = nblk + wn + j * 16 + rsel;
                    __bf16* C = (n < 1024) ? (__bf16*)C0 : (__bf16*)C1;
                    const int col = n & 1023;
                    float bv = bias[n];
#pragma unroll
                    for (int r = 0; r < 4; ++r) {
                        int m = mblk + wm + i * 16 + rq + r;
                        __builtin_nontemporal_store(
                            (__bf16)(acc[i][j][r] + bv), &C[(long)m * ldc + col]);
                    }
                }
            }
        }
    } else if constexpr (MODE == 1) {
        // ---- scores path: E = exp(s) bf16 + per-row partial sums ----
        __bf16* C = (__bf16*)C0 + (long)z * sC;
        float* psum = (float*)C1 + (long)z * 65536;   // [32][2048]
        float vsum[4][4];
#pragma unroll
        for (int i = 0; i < 4; ++i)
#pragma unroll
            for (int r = 0; r < 4; ++r) vsum[i][r] = 0.f;
#pragma unroll
        for (int i = 0; i < 4; ++i) {
#pragma unroll
            for (int j = 0; j < 4; ++j) {
                const int n = nblk + wn + j * 16 + rsel;
#pragma unroll
                for (int r = 0; r < 4; ++r) {
                    int m = mblk + wm + i * 16 + rq + r;
                    float e = __expf(acc[i][j][r] * scale);
                    __builtin_nontemporal_store((__bf16)e, &C[(long)m * ldc + n]);
                    vsum[i][r] += e;
                }
            }
        }
        // reduce over the 16 rsel lanes (cols) -> row sums over this wave's 64 cols
#pragma unroll
        for (int o = 1; o < 16; o <<= 1)
#pragma unroll
            for (int i = 0; i < 4; ++i)
#pragma unroll
                for (int r = 0; r < 4; ++r)
                    vsum[i][r] += __shfl_xor(vsum[i][r], o, 64);
        if (rsel == 0) {
            const int nb2 = (nblk + wn) >> 6;             // 0..31
#pragma unroll
            for (int i = 0; i < 4; ++i)
#pragma unroll
                for (int r = 0; r < 4; ++r)
                    psum[nb2 * 2048 + mblk + wm + i * 16 + rq + r] = vsum[i][r];
        }
    } else {
        // ---- PV path ----
        // (a) f32 attention-weight write for owned k-chunks; E re-read from
        //     global; nt stores (never re-read).
        {
            float* wout = (float*)C2 + (long)z * (2048L * 2048);
#pragma unroll
            for (int kc = 0; kc < 4; ++kc) {
                const int k0 = ((int)blockIdx.x + kc * 8) << 6;
#pragma unroll
                for (int it = 0; it < 4; ++it) {
                    const __bf16* ep = A + (long)(mblk + srow[it]) * lda + k0 + scol[it];
                    bf16x8 ch = *(const bf16x8*)ep;
                    const float iv = linv[srow[it]];
                    f32x4 w0, w1;
                    w0[0] = (float)ch[0] * iv; w0[1] = (float)ch[1] * iv;
                    w0[2] = (float)ch[2] * iv; w0[3] = (float)ch[3] * iv;
                    w1[0] = (float)ch[4] * iv; w1[1] = (float)ch[5] * iv;
                    w1[2] = (float)ch[6] * iv; w1[3] = (float)ch[7] * iv;
                    float* wp = wout + (long)(mblk + srow[it]) * 2048 + k0 + scol[it];
                    __builtin_nontemporal_store(w0, (f32x4*)wp);
                    __builtin_nontemporal_store(w1, (f32x4*)(wp + 4));
                }
            }
        }
        // (b) weighted sum: out = acc * linv
        float* Cz = (float*)C0 + (long)z * sC;
#pragma unroll
        for (int i = 0; i < 4; ++i) {
#pragma unroll
            for (int j = 0; j < 4; ++j) {
                const int n = nblk + wn + j * 16 + rsel;
#pragma unroll
                for (int r = 0; r < 4; ++r) {
                    int m = mblk + wm + i * 16 + rq + r;
                    __builtin_nontemporal_store(
                        acc[i][j][r] * linv[wm + i * 16 + rq + r],
                        &Cz[(long)m * ldc + n]);
                }
            }
        }
    }
}

// ---------------------------------------------------------------------------
extern "C" void kernel_launch(void* const* d_in, const int* in_sizes, int n_in,
                              void* d_out, int out_size, void* d_ws, size_t ws_size,
                              hipStream_t stream) {
    const float* x  = (const float*)d_in[0];
    const float* Wq = (const float*)d_in[1];
    const float* bq = (const float*)d_in[2];
    const float* Wk = (const float*)d_in[3];
    const float* bk = (const float*)d_in[4];
    const float* Wv = (const float*)d_in[5];
    const float* bv = (const float*)d_in[6];

    const int  S = 2048, H = 1024, I = 1024, B = 4;
    const long MS = (long)B * S;
    float* out_ws  = (float*)d_out;
    float* out_att = (float*)d_out + (long)B * S * H;

    char* w = (char*)d_ws;
    __bf16* x_bf   = (__bf16*)w; w += MS * I * 2;
    __bf16* wqkv   = (__bf16*)w; w += (long)3 * H * I * 2;
    float*  bias3  = (float*)w;  w += 4096 * 4;
    __bf16* q_bf   = (__bf16*)w; w += MS * H * 2;
    __bf16* k_bf   = (__bf16*)w; w += MS * H * 2;
    __bf16* vt_bf  = (__bf16*)w; w += MS * H * 2;
    __bf16* p_bf   = (__bf16*)w; w += (long)B * S * S * 2;
    // psum [4][32][2048] f32 = 1 MB carved from x_bf (dead after QKV)
    float* psum = (float*)x_bf;

    // 1) all converts + bias pack
    {
        long tot = 1048576 + 3 * 131072 + 384;
        cvt_all<<<dim3((unsigned)((tot + 255) / 256)), dim3(256), 0, stream>>>(
            x, Wq, Wk, Wv, bq, bk, bv, x_bf, wqkv, bias3);
    }

    // 2) fused QKV projection (V written pre-transposed): M=8192, N=3072, K=1024
    gemm_nt<0><<<dim3(24, 64, 1), dim3(256), 0, stream>>>(
        x_bf, wqkv, q_bf, k_bf, vt_bf, bias3,
        1024, 1024, 1024, 0, 0, 0, 1024, 1.f);

    // 3) scores: E = exp(QK^T/32) bf16 -> p_bf; row partial sums -> psum
    gemm_nt<1><<<dim3(16, 16, 4), dim3(256), 0, stream>>>(
        q_bf, k_bf, p_bf, psum, nullptr, nullptr,
        1024, 1024, 2048, (long)S * H, (long)S * H, (long)S * S, 1024, 0.03125f);

    // 4) PV on E: epilogue writes f32 attention weights + weighted sum
    gemm_nt<2><<<dim3(8, 16, 4), dim3(256), 0, stream>>>(
        p_bf, vt_bf, out_ws, psum, out_att, nullptr,
        2048, 2048, 1024, (long)S * S, (long)S * H, (long)S * H, 2048, 1.f);
}

// Round 10
// 299.625 us; speedup vs baseline: 1.2369x; 1.2369x over previous
//
#include <hip/hip_runtime.h>
#include <hip/hip_bf16.h>
#include <cstdint>

// ---------------------------------------------------------------------------
// SelfAttention: q,k,v = x@W{q,k,v}^T + b ; P = softmax(qk^T/sqrt(H)) ; out = P@v
// B=4, S=2048, H=I=1024. fp32 I/O, bf16 MFMA internally (tol 6.25e-3).
// R14 == R12 (verified 284.3 us): softmax folded into scores/PV epilogues;
//      PV w-write in epilogue from global E re-read. R13's nontemporal-store
//      experiment is reverted: FETCH unchanged (write-allocate theory false)
//      and WRITE inflated +34 MB (lost L2 write-merging), PV 70->100 us.
// ---------------------------------------------------------------------------

typedef __bf16 bf16x8 __attribute__((ext_vector_type(8)));
typedef float  f32x4  __attribute__((ext_vector_type(4)));

__device__ __forceinline__ void load_lds16(const __bf16* g, __bf16* l) {
    __builtin_amdgcn_global_load_lds(
        (const __attribute__((address_space(1))) void*)g,
        (__attribute__((address_space(3))) void*)l,
        16, 0, 0);
}

// ------------- merged fp32->bf16 converts + bias pack (1 launch) -----------
__global__ __launch_bounds__(256) void cvt_all(
        const float* __restrict__ x,
        const float* __restrict__ wq, const float* __restrict__ wk,
        const float* __restrict__ wv,
        const float* __restrict__ bq, const float* __restrict__ bk,
        const float* __restrict__ bv,
        __bf16* __restrict__ xb, __bf16* __restrict__ wb,
        float* __restrict__ bias3) {
    const long NX = 1048576, NW = 131072;
    long i = (long)blockIdx.x * 256 + threadIdx.x;
    const float* src; __bf16* dst; long c;
    if (i < NX) { src = x; dst = xb; c = i; }
    else if (i < NX + 3 * NW) {
        long j = i - NX;
        src = (j < NW) ? wq : (j < 2 * NW) ? wk : wv;
        c = j % NW;
        dst = wb + (j / NW) * (NW * 8);
    } else if (i < NX + 3 * NW + 384) {
        long cidx = i - (NX + 3 * NW);
        int seg = (int)(cidx >> 7);
        const float* bs = (seg == 0) ? bq : (seg == 1) ? bk : bv;
        long off = (cidx & 127) * 8;
        float4 a = *(const float4*)(bs + off);
        float4 b = *(const float4*)(bs + off + 4);
        *(float4*)(bias3 + cidx * 8)     = a;
        *(float4*)(bias3 + cidx * 8 + 4) = b;
        return;
    } else return;
    const float4* s4 = (const float4*)src;
    float4 a = s4[2 * c], b = s4[2 * c + 1];
    bf16x8 o;
    o[0] = (__bf16)a.x; o[1] = (__bf16)a.y; o[2] = (__bf16)a.z; o[3] = (__bf16)a.w;
    o[4] = (__bf16)b.x; o[5] = (__bf16)b.y; o[6] = (__bf16)b.z; o[7] = (__bf16)b.w;
    ((bf16x8*)dst)[c] = o;
}

// ---------------- NT bf16 GEMM: C[m,n] = sum_k A[m,k] * Bt[n,k] ------------
// 128x128 tile, BK=64, 4 waves (2x2 of 64x64), 16x16x32 MFMA, 4x4 frags/wave.
// LDS: 16B chunks, chunk (row,cs) holds cg = cs ^ (row&7).  Zero conflicts.
// MODE 0: fused QKV. n<2048 -> bf16=acc+bias to C0/C1 [m][n&1023];
//         n>=2048 -> V: LDS-transposed, written as vt[h][t] to C2.
// MODE 1: scores: bf16 E=exp(acc*scale) -> C0 (p_bf); row partial sums ->
//         C1 = psum[z][32][2048] (one writer per (z,nb2,row), no atomics).
// MODE 2: PV on unnormalized E: linv from psum (C1); epilogue writes f32
//         attention weights to C2 for owned k-chunks (E re-read from global,
//         L2-hot) and f32 = acc*linv -> C0 (weighted sum).
template <int MODE>
__global__ __launch_bounds__(256, 4) void gemm_nt(
        const __bf16* __restrict__ A, const __bf16* __restrict__ Bt,
        void* __restrict__ C0, void* __restrict__ C1, void* __restrict__ C2,
        const float* __restrict__ bias,
        int lda, int ldb, int ldc, long sA, long sB, long sC,
        int K, float scale) {
    __shared__ __bf16 smem[16384];      // lA | lB, reused as transpose buffer
    __shared__ float linv[128];         // MODE 2: per-row 1/sum
    __bf16* lA = smem;
    __bf16* lB = smem + 8192;

    const int tid  = threadIdx.x;
    const int lane = tid & 63;
    const int wave = tid >> 6;
    const int mblk = blockIdx.y * 128;
    const int nblk = blockIdx.x * 128;
    const int z    = blockIdx.z;
    A  += (long)z * sA;
    Bt += (long)z * sB;

    const int wm = (wave >> 1) * 64;
    const int wn = (wave & 1) * 64;

    f32x4 zero = {0.f, 0.f, 0.f, 0.f};
    f32x4 acc[4][4];
#pragma unroll
    for (int i = 0; i < 4; ++i)
#pragma unroll
        for (int j = 0; j < 4; ++j) acc[i][j] = zero;

    const int rsel = lane & 15;
    const int quad = lane >> 4;

    int srow[4], scol[4];
#pragma unroll
    for (int it = 0; it < 4; ++it) {
        int s  = tid + it * 256;
        srow[it] = s >> 3;
        scol[it] = ((s & 7) ^ (srow[it] & 7)) * 8;
    }

    if constexpr (MODE == 2) {
        // build linv[128] = 1/rowsum from 32 partials (coalesced, L2-hot)
        if (tid < 128) {
            const float* ps = (const float*)C1 + (long)z * 65536 + (mblk + tid);
            float ssum = 0.f;
#pragma unroll
            for (int nb = 0; nb < 32; ++nb) ssum += ps[nb * 2048];
            linv[tid] = 1.f / ssum;
        }
        // first in-loop __syncthreads() publishes linv before any use
    }

    for (int k0 = 0; k0 < K; k0 += 64) {
#pragma unroll
        for (int it = 0; it < 4; ++it) {
            int s = tid + it * 256;
            load_lds16(A  + (long)(mblk + srow[it]) * lda + k0 + scol[it], lA + s * 8);
            load_lds16(Bt + (long)(nblk + srow[it]) * ldb + k0 + scol[it], lB + s * 8);
        }
        __syncthreads();

#pragma unroll
        for (int half = 0; half < 2; ++half) {
            const int cq = quad + half * 4;
            bf16x8 fa[4], fb[4];
#pragma unroll
            for (int i = 0; i < 4; ++i) {
                int ra = wm + i * 16 + rsel;
                fa[i] = *(const bf16x8*)&lA[(ra * 8 + (cq ^ (ra & 7))) * 8];
                int rb = wn + i * 16 + rsel;
                fb[i] = *(const bf16x8*)&lB[(rb * 8 + (cq ^ (rb & 7))) * 8];
            }
#pragma unroll
            for (int i = 0; i < 4; ++i)
#pragma unroll
                for (int j = 0; j < 4; ++j)
                    acc[i][j] = __builtin_amdgcn_mfma_f32_16x16x32_bf16(
                        fa[i], fb[j], acc[i][j], 0, 0, 0);
        }
        __syncthreads();
    }

    // epilogue: lane holds C[m = wm+i*16+quad*4+r][n = wn+j*16+rsel]
    const int rq = quad * 4;
    if constexpr (MODE == 0) {
        if (nblk >= 2048) {
            // ---- V path: transpose tile via LDS, store vt[h][t] ----
            __bf16* tbuf = smem;
#pragma unroll
            for (int i = 0; i < 4; ++i) {
#pragma unroll
                for (int j = 0; j < 4; ++j) {
                    const int n_loc = wn + j * 16 + rsel;
                    const float bv = bias[nblk + n_loc];
                    const int m_loc = wm + i * 16 + rq;       // +r, r=0..3
                    const int c  = m_loc >> 3;
                    const int cs = c ^ (n_loc & 15);
                    __bf16* dst = &tbuf[n_loc * 128 + cs * 8 + (m_loc & 7)];
                    __bf16 tmp[4];
#pragma unroll
                    for (int r = 0; r < 4; ++r) tmp[r] = (__bf16)(acc[i][j][r] + bv);
                    *(uint64_t*)dst = *(const uint64_t*)tmp;
                }
            }
            __syncthreads();
            {
                __bf16* vt = (__bf16*)C2;
                const int n_loc = tid & 127;
                const int cpart = tid >> 7;
                const long b = mblk >> 11;                    // batch
                const long t0 = mblk & 2047;
                const long h  = nblk - 2048 + n_loc;
                __bf16* gdst = vt + b * (1024L * 2048) + h * 2048 + t0;
#pragma unroll
                for (int s = 0; s < 8; ++s) {
                    int c  = cpart * 8 + s;
                    int cs = c ^ (n_loc & 15);
                    bf16x8 vchunk = *(const bf16x8*)&tbuf[n_loc * 128 + cs * 8];
                    *(bf16x8*)(gdst + c * 8) = vchunk;
                }
            }
        } else {
            // ---- Q/K path: normal [m][n] bf16 store ----
#pragma unroll
            for (int i = 0; i < 4; ++i) {
#pragma unroll
                for (int j = 0; j < 4; ++j) {
                    const int n = nblk + wn + j * 16 + rsel;
                    __bf16* C = (n < 1024) ? (__bf16*)C0 : (__bf16*)C1;
                    const int col = n & 1023;
                    float bv = bias[n];
#pragma unroll
                    for (int r = 0; r < 4; ++r) {
                        int m = mblk + wm + i * 16 + rq + r;
                        C[(long)m * ldc + col] = (__bf16)(acc[i][j][r] + bv);
                    }
                }
            }
        }
    } else if constexpr (MODE == 1) {
        // ---- scores path: E = exp(s) bf16 + per-row partial sums ----
        __bf16* C = (__bf16*)C0 + (long)z * sC;
        float* psum = (float*)C1 + (long)z * 65536;   // [32][2048]
        float vsum[4][4];
#pragma unroll
        for (int i = 0; i < 4; ++i)
#pragma unroll
            for (int r = 0; r < 4; ++r) vsum[i][r] = 0.f;
#pragma unroll
        for (int i = 0; i < 4; ++i) {
#pragma unroll
            for (int j = 0; j < 4; ++j) {
                const int n = nblk + wn + j * 16 + rsel;
#pragma unroll
                for (int r = 0; r < 4; ++r) {
                    int m = mblk + wm + i * 16 + rq + r;
                    float e = __expf(acc[i][j][r] * scale);
                    C[(long)m * ldc + n] = (__bf16)e;
                    vsum[i][r] += e;
                }
            }
        }
        // reduce over the 16 rsel lanes (cols) -> row sums over this wave's 64 cols
#pragma unroll
        for (int o = 1; o < 16; o <<= 1)
#pragma unroll
            for (int i = 0; i < 4; ++i)
#pragma unroll
                for (int r = 0; r < 4; ++r)
                    vsum[i][r] += __shfl_xor(vsum[i][r], o, 64);
        if (rsel == 0) {
            const int nb2 = (nblk + wn) >> 6;             // 0..31
#pragma unroll
            for (int i = 0; i < 4; ++i)
#pragma unroll
                for (int r = 0; r < 4; ++r)
                    psum[nb2 * 2048 + mblk + wm + i * 16 + rq + r] = vsum[i][r];
        }
    } else {
        // ---- PV path ----
        // (a) f32 attention-weight write for owned k-chunks; E re-read from
        //     global (own-XCD L2-hot: this block staged exactly these chunks).
        {
            float* wout = (float*)C2 + (long)z * (2048L * 2048);
#pragma unroll
            for (int kc = 0; kc < 4; ++kc) {
                const int k0 = ((int)blockIdx.x + kc * 8) << 6;
#pragma unroll
                for (int it = 0; it < 4; ++it) {
                    const __bf16* ep = A + (long)(mblk + srow[it]) * lda + k0 + scol[it];
                    bf16x8 ch = *(const bf16x8*)ep;
                    const float iv = linv[srow[it]];
                    float4 w0, w1;
                    w0.x = (float)ch[0] * iv; w0.y = (float)ch[1] * iv;
                    w0.z = (float)ch[2] * iv; w0.w = (float)ch[3] * iv;
                    w1.x = (float)ch[4] * iv; w1.y = (float)ch[5] * iv;
                    w1.z = (float)ch[6] * iv; w1.w = (float)ch[7] * iv;
                    float* wp = wout + (long)(mblk + srow[it]) * 2048 + k0 + scol[it];
                    *(float4*)wp       = w0;
                    *(float4*)(wp + 4) = w1;
                }
            }
        }
        // (b) weighted sum: out = acc * linv
        float* Cz = (float*)C0 + (long)z * sC;
#pragma unroll
        for (int i = 0; i < 4; ++i) {
#pragma unroll
            for (int j = 0; j < 4; ++j) {
                const int n = nblk + wn + j * 16 + rsel;
#pragma unroll
                for (int r = 0; r < 4; ++r) {
                    int m = mblk + wm + i * 16 + rq + r;
                    Cz[(long)m * ldc + n] = acc[i][j][r] * linv[wm + i * 16 + rq + r];
                }
            }
        }
    }
}

// ---------------------------------------------------------------------------
extern "C" void kernel_launch(void* const* d_in, const int* in_sizes, int n_in,
                              void* d_out, int out_size, void* d_ws, size_t ws_size,
                              hipStream_t stream) {
    const float* x  = (const float*)d_in[0];
    const float* Wq = (const float*)d_in[1];
    const float* bq = (const float*)d_in[2];
    const float* Wk = (const float*)d_in[3];
    const float* bk = (const float*)d_in[4];
    const float* Wv = (const float*)d_in[5];
    const float* bv = (const float*)d_in[6];

    const int  S = 2048, H = 1024, I = 1024, B = 4;
    const long MS = (long)B * S;
    float* out_ws  = (float*)d_out;
    float* out_att = (float*)d_out + (long)B * S * H;

    char* w = (char*)d_ws;
    __bf16* x_bf   = (__bf16*)w; w += MS * I * 2;
    __bf16* wqkv   = (__bf16*)w; w += (long)3 * H * I * 2;
    float*  bias3  = (float*)w;  w += 4096 * 4;
    __bf16* q_bf   = (__bf16*)w; w += MS * H * 2;
    __bf16* k_bf   = (__bf16*)w; w += MS * H * 2;
    __bf16* vt_bf  = (__bf16*)w; w += MS * H * 2;
    __bf16* p_bf   = (__bf16*)w; w += (long)B * S * S * 2;
    // psum [4][32][2048] f32 = 1 MB carved from x_bf (dead after QKV)
    float* psum = (float*)x_bf;

    // 1) all converts + bias pack
    {
        long tot = 1048576 + 3 * 131072 + 384;
        cvt_all<<<dim3((unsigned)((tot + 255) / 256)), dim3(256), 0, stream>>>(
            x, Wq, Wk, Wv, bq, bk, bv, x_bf, wqkv, bias3);
    }

    // 2) fused QKV projection (V written pre-transposed): M=8192, N=3072, K=1024
    gemm_nt<0><<<dim3(24, 64, 1), dim3(256), 0, stream>>>(
        x_bf, wqkv, q_bf, k_bf, vt_bf, bias3,
        1024, 1024, 1024, 0, 0, 0, 1024, 1.f);

    // 3) scores: E = exp(QK^T/32) bf16 -> p_bf; row partial sums -> psum
    gemm_nt<1><<<dim3(16, 16, 4), dim3(256), 0, stream>>>(
        q_bf, k_bf, p_bf, psum, nullptr, nullptr,
        1024, 1024, 2048, (long)S * H, (long)S * H, (long)S * S, 1024, 0.03125f);

    // 4) PV on E: epilogue writes f32 attention weights + weighted sum
    gemm_nt<2><<<dim3(8, 16, 4), dim3(256), 0, stream>>>(
        p_bf, vt_bf, out_ws, psum, out_att, nullptr,
        2048, 2048, 1024, (long)S * S, (long)S * H, (long)S * H, 2048, 1.f);
}

// Round 11
// 289.705 us; speedup vs baseline: 1.2793x; 1.0342x over previous
//
#include <hip/hip_runtime.h>
#include <hip/hip_bf16.h>
#include <cstdint>

// ---------------------------------------------------------------------------
// SelfAttention: q,k,v = x@W{q,k,v}^T + b ; P = softmax(qk^T/sqrt(H)) ; out = P@v
// B=4, S=2048, H=I=1024. fp32 I/O, bf16 MFMA internally (tol 6.25e-3).
// R15: R12/R14 + XCD co-location swizzle (T1) on scores and PV.
//      Default xcd = bid%8 puts the 8 (PV) / 16 (scores) blocks sharing one
//      E/Q A-panel on 8 DIFFERENT XCDs -> each panel filled into 8 L2s
//      (PV FETCH 167 MB vs ~50 mandatory). Swizzle: r=bid&7 stays fixed
//      within a panel-sharing group so the group lands on ONE XCD's L2.
//      Bijective; MODE 0 (QKV, structure-bound) untouched.
// ---------------------------------------------------------------------------

typedef __bf16 bf16x8 __attribute__((ext_vector_type(8)));
typedef float  f32x4  __attribute__((ext_vector_type(4)));

__device__ __forceinline__ void load_lds16(const __bf16* g, __bf16* l) {
    __builtin_amdgcn_global_load_lds(
        (const __attribute__((address_space(1))) void*)g,
        (__attribute__((address_space(3))) void*)l,
        16, 0, 0);
}

// ------------- merged fp32->bf16 converts + bias pack (1 launch) -----------
__global__ __launch_bounds__(256) void cvt_all(
        const float* __restrict__ x,
        const float* __restrict__ wq, const float* __restrict__ wk,
        const float* __restrict__ wv,
        const float* __restrict__ bq, const float* __restrict__ bk,
        const float* __restrict__ bv,
        __bf16* __restrict__ xb, __bf16* __restrict__ wb,
        float* __restrict__ bias3) {
    const long NX = 1048576, NW = 131072;
    long i = (long)blockIdx.x * 256 + threadIdx.x;
    const float* src; __bf16* dst; long c;
    if (i < NX) { src = x; dst = xb; c = i; }
    else if (i < NX + 3 * NW) {
        long j = i - NX;
        src = (j < NW) ? wq : (j < 2 * NW) ? wk : wv;
        c = j % NW;
        dst = wb + (j / NW) * (NW * 8);
    } else if (i < NX + 3 * NW + 384) {
        long cidx = i - (NX + 3 * NW);
        int seg = (int)(cidx >> 7);
        const float* bs = (seg == 0) ? bq : (seg == 1) ? bk : bv;
        long off = (cidx & 127) * 8;
        float4 a = *(const float4*)(bs + off);
        float4 b = *(const float4*)(bs + off + 4);
        *(float4*)(bias3 + cidx * 8)     = a;
        *(float4*)(bias3 + cidx * 8 + 4) = b;
        return;
    } else return;
    const float4* s4 = (const float4*)src;
    float4 a = s4[2 * c], b = s4[2 * c + 1];
    bf16x8 o;
    o[0] = (__bf16)a.x; o[1] = (__bf16)a.y; o[2] = (__bf16)a.z; o[3] = (__bf16)a.w;
    o[4] = (__bf16)b.x; o[5] = (__bf16)b.y; o[6] = (__bf16)b.z; o[7] = (__bf16)b.w;
    ((bf16x8*)dst)[c] = o;
}

// ---------------- NT bf16 GEMM: C[m,n] = sum_k A[m,k] * Bt[n,k] ------------
// 128x128 tile, BK=64, 4 waves (2x2 of 64x64), 16x16x32 MFMA, 4x4 frags/wave.
// LDS: 16B chunks, chunk (row,cs) holds cg = cs ^ (row&7).  Zero conflicts.
// MODE 0: fused QKV. n<2048 -> bf16=acc+bias to C0/C1 [m][n&1023];
//         n>=2048 -> V: LDS-transposed, written as vt[h][t] to C2.
// MODE 1: scores: bf16 E=exp(acc*scale) -> C0 (p_bf); row partial sums ->
//         C1 = psum[z][32][2048]. XCD-swizzled (grid 16x16x4).
// MODE 2: PV on unnormalized E: linv from psum (C1); epilogue writes f32
//         attention weights to C2 for owned k-chunks (E re-read, L2-hot)
//         and f32 = acc*linv -> C0. XCD-swizzled (grid 8x16x4).
template <int MODE>
__global__ __launch_bounds__(256, 4) void gemm_nt(
        const __bf16* __restrict__ A, const __bf16* __restrict__ Bt,
        void* __restrict__ C0, void* __restrict__ C1, void* __restrict__ C2,
        const float* __restrict__ bias,
        int lda, int ldb, int ldc, long sA, long sB, long sC,
        int K, float scale) {
    __shared__ __bf16 smem[16384];      // lA | lB, reused as transpose buffer
    __shared__ float linv[128];         // MODE 2: per-row 1/sum
    __bf16* lA = smem;
    __bf16* lB = smem + 8192;

    const int tid  = threadIdx.x;
    const int lane = tid & 63;
    const int wave = tid >> 6;

    // ---- block-index mapping (XCD co-location for MODE 1/2) ----
    int mblk, nblk, z;
    if constexpr (MODE == 0) {
        mblk = blockIdx.y * 128; nblk = blockIdx.x * 128; z = blockIdx.z;
    } else if constexpr (MODE == 1) {
        // grid (16,16,4): groups of 16 x-blocks share the Q panel (y,z).
        int bid = (int)blockIdx.x + ((int)blockIdx.y << 4) + ((int)blockIdx.z << 8);
        int r = bid & 7, j = bid >> 3;
        int xe = j & 15, g = r + ((j >> 4) << 3);     // g in 0..63
        nblk = xe * 128; mblk = (g & 15) * 128; z = g >> 4;
    } else {
        // grid (8,16,4): groups of 8 x-blocks share the E panel (y,z).
        int bid = (int)blockIdx.x + ((int)blockIdx.y << 3) + ((int)blockIdx.z << 7);
        int r = bid & 7, j = bid >> 3;
        int xe = j & 7, g = r + ((j >> 3) << 3);      // g in 0..63
        nblk = xe * 128; mblk = (g & 15) * 128; z = g >> 4;
    }
    A  += (long)z * sA;
    Bt += (long)z * sB;

    const int wm = (wave >> 1) * 64;
    const int wn = (wave & 1) * 64;

    f32x4 zero = {0.f, 0.f, 0.f, 0.f};
    f32x4 acc[4][4];
#pragma unroll
    for (int i = 0; i < 4; ++i)
#pragma unroll
        for (int j = 0; j < 4; ++j) acc[i][j] = zero;

    const int rsel = lane & 15;
    const int quad = lane >> 4;

    int srow[4], scol[4];
#pragma unroll
    for (int it = 0; it < 4; ++it) {
        int s  = tid + it * 256;
        srow[it] = s >> 3;
        scol[it] = ((s & 7) ^ (srow[it] & 7)) * 8;
    }

    if constexpr (MODE == 2) {
        // build linv[128] = 1/rowsum from 32 partials (coalesced, L2-hot)
        if (tid < 128) {
            const float* ps = (const float*)C1 + (long)z * 65536 + (mblk + tid);
            float ssum = 0.f;
#pragma unroll
            for (int nb = 0; nb < 32; ++nb) ssum += ps[nb * 2048];
            linv[tid] = 1.f / ssum;
        }
        // first in-loop __syncthreads() publishes linv before any use
    }

    for (int k0 = 0; k0 < K; k0 += 64) {
#pragma unroll
        for (int it = 0; it < 4; ++it) {
            int s = tid + it * 256;
            load_lds16(A  + (long)(mblk + srow[it]) * lda + k0 + scol[it], lA + s * 8);
            load_lds16(Bt + (long)(nblk + srow[it]) * ldb + k0 + scol[it], lB + s * 8);
        }
        __syncthreads();

#pragma unroll
        for (int half = 0; half < 2; ++half) {
            const int cq = quad + half * 4;
            bf16x8 fa[4], fb[4];
#pragma unroll
            for (int i = 0; i < 4; ++i) {
                int ra = wm + i * 16 + rsel;
                fa[i] = *(const bf16x8*)&lA[(ra * 8 + (cq ^ (ra & 7))) * 8];
                int rb = wn + i * 16 + rsel;
                fb[i] = *(const bf16x8*)&lB[(rb * 8 + (cq ^ (rb & 7))) * 8];
            }
#pragma unroll
            for (int i = 0; i < 4; ++i)
#pragma unroll
                for (int j = 0; j < 4; ++j)
                    acc[i][j] = __builtin_amdgcn_mfma_f32_16x16x32_bf16(
                        fa[i], fb[j], acc[i][j], 0, 0, 0);
        }
        __syncthreads();
    }

    // epilogue: lane holds C[m = wm+i*16+quad*4+r][n = wn+j*16+rsel]
    const int rq = quad * 4;
    if constexpr (MODE == 0) {
        if (nblk >= 2048) {
            // ---- V path: transpose tile via LDS, store vt[h][t] ----
            __bf16* tbuf = smem;
#pragma unroll
            for (int i = 0; i < 4; ++i) {
#pragma unroll
                for (int j = 0; j < 4; ++j) {
                    const int n_loc = wn + j * 16 + rsel;
                    const float bv = bias[nblk + n_loc];
                    const int m_loc = wm + i * 16 + rq;       // +r, r=0..3
                    const int c  = m_loc >> 3;
                    const int cs = c ^ (n_loc & 15);
                    __bf16* dst = &tbuf[n_loc * 128 + cs * 8 + (m_loc & 7)];
                    __bf16 tmp[4];
#pragma unroll
                    for (int r = 0; r < 4; ++r) tmp[r] = (__bf16)(acc[i][j][r] + bv);
                    *(uint64_t*)dst = *(const uint64_t*)tmp;
                }
            }
            __syncthreads();
            {
                __bf16* vt = (__bf16*)C2;
                const int n_loc = tid & 127;
                const int cpart = tid >> 7;
                const long b = mblk >> 11;                    // batch
                const long t0 = mblk & 2047;
                const long h  = nblk - 2048 + n_loc;
                __bf16* gdst = vt + b * (1024L * 2048) + h * 2048 + t0;
#pragma unroll
                for (int s = 0; s < 8; ++s) {
                    int c  = cpart * 8 + s;
                    int cs = c ^ (n_loc & 15);
                    bf16x8 vchunk = *(const bf16x8*)&tbuf[n_loc * 128 + cs * 8];
                    *(bf16x8*)(gdst + c * 8) = vchunk;
                }
            }
        } else {
            // ---- Q/K path: normal [m][n] bf16 store ----
#pragma unroll
            for (int i = 0; i < 4; ++i) {
#pragma unroll
                for (int j = 0; j < 4; ++j) {
                    const int n = nblk + wn + j * 16 + rsel;
                    __bf16* C = (n < 1024) ? (__bf16*)C0 : (__bf16*)C1;
                    const int col = n & 1023;
                    float bv = bias[n];
#pragma unroll
                    for (int r = 0; r < 4; ++r) {
                        int m = mblk + wm + i * 16 + rq + r;
                        C[(long)m * ldc + col] = (__bf16)(acc[i][j][r] + bv);
                    }
                }
            }
        }
    } else if constexpr (MODE == 1) {
        // ---- scores path: E = exp(s) bf16 + per-row partial sums ----
        __bf16* C = (__bf16*)C0 + (long)z * sC;
        float* psum = (float*)C1 + (long)z * 65536;   // [32][2048]
        float vsum[4][4];
#pragma unroll
        for (int i = 0; i < 4; ++i)
#pragma unroll
            for (int r = 0; r < 4; ++r) vsum[i][r] = 0.f;
#pragma unroll
        for (int i = 0; i < 4; ++i) {
#pragma unroll
            for (int j = 0; j < 4; ++j) {
                const int n = nblk + wn + j * 16 + rsel;
#pragma unroll
                for (int r = 0; r < 4; ++r) {
                    int m = mblk + wm + i * 16 + rq + r;
                    float e = __expf(acc[i][j][r] * scale);
                    C[(long)m * ldc + n] = (__bf16)e;
                    vsum[i][r] += e;
                }
            }
        }
        // reduce over the 16 rsel lanes (cols) -> row sums over this wave's 64 cols
#pragma unroll
        for (int o = 1; o < 16; o <<= 1)
#pragma unroll
            for (int i = 0; i < 4; ++i)
#pragma unroll
                for (int r = 0; r < 4; ++r)
                    vsum[i][r] += __shfl_xor(vsum[i][r], o, 64);
        if (rsel == 0) {
            const int nb2 = (nblk + wn) >> 6;             // 0..31
#pragma unroll
            for (int i = 0; i < 4; ++i)
#pragma unroll
                for (int r = 0; r < 4; ++r)
                    psum[nb2 * 2048 + mblk + wm + i * 16 + rq + r] = vsum[i][r];
        }
    } else {
        // ---- PV path ----
        // (a) f32 attention-weight write for owned k-chunks; E re-read from
        //     global (own-XCD L2-hot: this block staged exactly these chunks).
        {
            float* wout = (float*)C2 + (long)z * (2048L * 2048);
            const int xown = nblk >> 7;                   // owned chunk residue
#pragma unroll
            for (int kc = 0; kc < 4; ++kc) {
                const int k0 = (xown + kc * 8) << 6;
#pragma unroll
                for (int it = 0; it < 4; ++it) {
                    const __bf16* ep = A + (long)(mblk + srow[it]) * lda + k0 + scol[it];
                    bf16x8 ch = *(const bf16x8*)ep;
                    const float iv = linv[srow[it]];
                    float4 w0, w1;
                    w0.x = (float)ch[0] * iv; w0.y = (float)ch[1] * iv;
                    w0.z = (float)ch[2] * iv; w0.w = (float)ch[3] * iv;
                    w1.x = (float)ch[4] * iv; w1.y = (float)ch[5] * iv;
                    w1.z = (float)ch[6] * iv; w1.w = (float)ch[7] * iv;
                    float* wp = wout + (long)(mblk + srow[it]) * 2048 + k0 + scol[it];
                    *(float4*)wp       = w0;
                    *(float4*)(wp + 4) = w1;
                }
            }
        }
        // (b) weighted sum: out = acc * linv
        float* Cz = (float*)C0 + (long)z * sC;
#pragma unroll
        for (int i = 0; i < 4; ++i) {
#pragma unroll
            for (int j = 0; j < 4; ++j) {
                const int n = nblk + wn + j * 16 + rsel;
#pragma unroll
                for (int r = 0; r < 4; ++r) {
                    int m = mblk + wm + i * 16 + rq + r;
                    Cz[(long)m * ldc + n] = acc[i][j][r] * linv[wm + i * 16 + rq + r];
                }
            }
        }
    }
}

// ---------------------------------------------------------------------------
extern "C" void kernel_launch(void* const* d_in, const int* in_sizes, int n_in,
                              void* d_out, int out_size, void* d_ws, size_t ws_size,
                              hipStream_t stream) {
    const float* x  = (const float*)d_in[0];
    const float* Wq = (const float*)d_in[1];
    const float* bq = (const float*)d_in[2];
    const float* Wk = (const float*)d_in[3];
    const float* bk = (const float*)d_in[4];
    const float* Wv = (const float*)d_in[5];
    const float* bv = (const float*)d_in[6];

    const int  S = 2048, H = 1024, I = 1024, B = 4;
    const long MS = (long)B * S;
    float* out_ws  = (float*)d_out;
    float* out_att = (float*)d_out + (long)B * S * H;

    char* w = (char*)d_ws;
    __bf16* x_bf   = (__bf16*)w; w += MS * I * 2;
    __bf16* wqkv   = (__bf16*)w; w += (long)3 * H * I * 2;
    float*  bias3  = (float*)w;  w += 4096 * 4;
    __bf16* q_bf   = (__bf16*)w; w += MS * H * 2;
    __bf16* k_bf   = (__bf16*)w; w += MS * H * 2;
    __bf16* vt_bf  = (__bf16*)w; w += MS * H * 2;
    __bf16* p_bf   = (__bf16*)w; w += (long)B * S * S * 2;
    // psum [4][32][2048] f32 = 1 MB carved from x_bf (dead after QKV)
    float* psum = (float*)x_bf;

    // 1) all converts + bias pack
    {
        long tot = 1048576 + 3 * 131072 + 384;
        cvt_all<<<dim3((unsigned)((tot + 255) / 256)), dim3(256), 0, stream>>>(
            x, Wq, Wk, Wv, bq, bk, bv, x_bf, wqkv, bias3);
    }

    // 2) fused QKV projection (V written pre-transposed): M=8192, N=3072, K=1024
    gemm_nt<0><<<dim3(24, 64, 1), dim3(256), 0, stream>>>(
        x_bf, wqkv, q_bf, k_bf, vt_bf, bias3,
        1024, 1024, 1024, 0, 0, 0, 1024, 1.f);

    // 3) scores: E = exp(QK^T/32) bf16 -> p_bf; row partial sums -> psum
    gemm_nt<1><<<dim3(16, 16, 4), dim3(256), 0, stream>>>(
        q_bf, k_bf, p_bf, psum, nullptr, nullptr,
        1024, 1024, 2048, (long)S * H, (long)S * H, (long)S * S, 1024, 0.03125f);

    // 4) PV on E: epilogue writes f32 attention weights + weighted sum
    gemm_nt<2><<<dim3(8, 16, 4), dim3(256), 0, stream>>>(
        p_bf, vt_bf, out_ws, psum, out_att, nullptr,
        2048, 2048, 1024, (long)S * S, (long)S * H, (long)S * H, 2048, 1.f);
}